// Round 3
// baseline (792.818 us; speedup 1.0000x reference)
//
#include <hip/hip_runtime.h>
#include <cstdint>
#include <cstddef>

// AttnBlock: B=4, C=512, H=W=64 (N=4096). All-fp32 I/O, bf16 MFMA internally.
// R3: fused flash-attention kernel replaces staged QK^T/softmax/PV/reduce.
//     Projections unchanged (R2's double-buffered gemm_nt).

#define CDIM 512
#define NSP  4096
#define NB   4
#define KVB  64
#define QB   64

using bf16x8 = __attribute__((ext_vector_type(8))) __bf16;
using f32x4  = __attribute__((ext_vector_type(4))) float;
using u16x4  = __attribute__((ext_vector_type(4))) unsigned short;

__device__ __forceinline__ unsigned short f2bf(float f) {
  unsigned int u = __float_as_uint(f);
  u += 0x7fffu + ((u >> 16) & 1u);
  return (unsigned short)(u >> 16);
}

__device__ __forceinline__ void async_copy16(const unsigned short* g, unsigned short* l) {
  __builtin_amdgcn_global_load_lds(
      (const __attribute__((address_space(1))) void*)g,
      (__attribute__((address_space(3))) void*)l, 16, 0, 0);
}

// ---------------- GroupNorm stats: one block per (b, group) ----------------
__global__ __launch_bounds__(256) void gn_stats(const float* __restrict__ x,
                                                float* __restrict__ stats) {
  const size_t base = (size_t)blockIdx.x * 65536;  // 16 ch * 4096, contiguous
  const float4* p = (const float4*)(x + base);
  float s = 0.f, ss = 0.f;
  for (int i = threadIdx.x; i < 16384; i += 256) {
    float4 v = p[i];
    s  += v.x + v.y + v.z + v.w;
    ss += v.x*v.x + v.y*v.y + v.z*v.z + v.w*v.w;
  }
  for (int off = 32; off; off >>= 1) {
    s  += __shfl_xor(s, off);
    ss += __shfl_xor(ss, off);
  }
  __shared__ float rs[4], rss[4];
  const int w = threadIdx.x >> 6;
  if ((threadIdx.x & 63) == 0) { rs[w] = s; rss[w] = ss; }
  __syncthreads();
  if (threadIdx.x == 0) {
    float S  = rs[0] + rs[1] + rs[2] + rs[3];
    float SS = rss[0] + rss[1] + rss[2] + rss[3];
    float mean = S * (1.f / 65536.f);
    float var  = SS * (1.f / 65536.f) - mean * mean;
    stats[2 * blockIdx.x]     = mean;
    stats[2 * blockIdx.x + 1] = rsqrtf(var + 1e-6f);
  }
}

// ------------- normalize + transpose: x(B,C,N) f32 -> Hnt(B,N,C) bf16 -------
__global__ __launch_bounds__(256) void norm_transpose(
    const float* __restrict__ x, const float* __restrict__ stats,
    const float* __restrict__ gns, const float* __restrict__ gnb,
    unsigned short* __restrict__ hnt) {
  __shared__ float tile[64][65];
  const int b  = blockIdx.z;
  const int c0 = blockIdx.y * 64, n0 = blockIdx.x * 64;
  const int tx = threadIdx.x & 63, ty = threadIdx.x >> 6;
  for (int i = 0; i < 16; ++i) {
    int cl = ty * 16 + i;
    int c  = c0 + cl;
    int g  = c >> 4;
    float mean = stats[(b * 32 + g) * 2];
    float rstd = stats[(b * 32 + g) * 2 + 1];
    float v = x[((size_t)(b * CDIM + c)) * NSP + n0 + tx];
    tile[cl][tx] = (v - mean) * rstd * gns[c] + gnb[c];
  }
  __syncthreads();
  for (int i = 0; i < 16; ++i) {
    int nl = ty * 16 + i;
    hnt[((size_t)(b * NSP + n0 + nl)) * CDIM + c0 + tx] = f2bf(tile[tx][nl]);
  }
}

// ---------------- fp32 -> bf16 weight conversion (4 weights, one launch) ----
__global__ __launch_bounds__(256) void weights_to_bf16(
    const float* __restrict__ w0, const float* __restrict__ w1,
    const float* __restrict__ w2, const float* __restrict__ w3,
    unsigned short* __restrict__ o0, unsigned short* __restrict__ o1,
    unsigned short* __restrict__ o2, unsigned short* __restrict__ o3) {
  const float* s; unsigned short* o;
  switch (blockIdx.y) {
    case 0: s = w0; o = o0; break;
    case 1: s = w1; o = o1; break;
    case 2: s = w2; o = o2; break;
    default: s = w3; o = o3; break;
  }
  int i = blockIdx.x * 256 + threadIdx.x;
  float4 v = ((const float4*)s)[i];
  u16x4 r = {f2bf(v.x), f2bf(v.y), f2bf(v.z), f2bf(v.w)};
  *(u16x4*)(o + (size_t)i * 4) = r;
}

// ---------------- NT GEMM: D[M,N] = scale * A[M,K] @ Bt[N,K]^T ----------------
// BIAS_MODE: 0 none, 1 per-row (bias[m]), 2 per-col (bias[n])
template <int BIAS_MODE, int OUT_BF16, int RESID>
__global__ __launch_bounds__(256) void gemm_nt(
    const unsigned short* __restrict__ A, const unsigned short* __restrict__ Bt,
    void* __restrict__ Dv, const float* __restrict__ bias,
    const float* __restrict__ resid, int M, int N, int K, float scale,
    long sA, long sB, long sD, long sR) {
  __shared__ unsigned short lsA[2][128 * 32];
  __shared__ unsigned short lsB[2][128 * 32];
  const int tid = threadIdx.x;
  const int w = tid >> 6, lane = tid & 63;
  const int wr = w >> 1, wc = w & 1;
  const int b = blockIdx.z;
  const int bm0 = blockIdx.y * 128, bn0 = blockIdx.x * 128;
  const unsigned short* Ab = A + (size_t)b * sA;
  const unsigned short* Bb = Bt + (size_t)b * sB;

  f32x4 acc[4][4] = {};
  const int r0  = w * 16 + (lane >> 2);
  const int kof = (lane & 3) * 8;
  const int fr  = lane & 15, kf = (lane >> 4) * 8;

  for (int it = 0; it < 2; ++it) {
    int row = it * 64 + r0;
    async_copy16(Ab + (size_t)(bm0 + row) * K + kof, &lsA[0][row * 32 + kof]);
    async_copy16(Bb + (size_t)(bn0 + row) * K + kof, &lsB[0][row * 32 + kof]);
  }
  __syncthreads();

  int cur = 0;
  for (int k0 = 0; k0 < K; k0 += 32) {
    const int nk = k0 + 32;
    if (nk < K) {
      for (int it = 0; it < 2; ++it) {
        int row = it * 64 + r0;
        async_copy16(Ab + (size_t)(bm0 + row) * K + nk + kof, &lsA[cur ^ 1][row * 32 + kof]);
        async_copy16(Bb + (size_t)(bn0 + row) * K + nk + kof, &lsB[cur ^ 1][row * 32 + kof]);
      }
    }
    bf16x8 af[4], bff[4];
    for (int i = 0; i < 4; ++i) {
      af[i]  = *(const bf16x8*)(&lsA[cur][(wr * 64 + i * 16 + fr) * 32 + kf]);
      bff[i] = *(const bf16x8*)(&lsB[cur][(wc * 64 + i * 16 + fr) * 32 + kf]);
    }
    for (int i = 0; i < 4; ++i)
      for (int j = 0; j < 4; ++j)
        acc[i][j] = __builtin_amdgcn_mfma_f32_16x16x32_bf16(af[i], bff[j], acc[i][j], 0, 0, 0);
    __syncthreads();
    cur ^= 1;
  }

  const int col_l = lane & 15, row_l = (lane >> 4) * 4;
  for (int i = 0; i < 4; ++i)
    for (int j = 0; j < 4; ++j) {
      int gr = bm0 + wr * 64 + i * 16 + row_l;
      int gc = bn0 + wc * 64 + j * 16 + col_l;
      for (int r = 0; r < 4; ++r) {
        float v = acc[i][j][r] * scale;
        if (BIAS_MODE == 1) v += bias[gr + r];
        if (BIAS_MODE == 2) v += bias[gc];
        if (RESID) v += resid[(size_t)b * sR + (size_t)(gr + r) * N + gc];
        if (OUT_BF16)
          ((unsigned short*)Dv)[(size_t)b * sD + (size_t)(gr + r) * N + gc] = f2bf(v);
        else
          ((float*)Dv)[(size_t)b * sD + (size_t)(gr + r) * N + gc] = v;
      }
    }
}

// ---------------- fused flash attention ----------------
// grid (64 qblocks, NB). 512 threads = 8 waves.
// wave w: rs=w>>1 (S row strip 16*rs), h=w&1 (S col half 32*h); O cols [64w,+64).
// qt/kt: (B,4096,512) bf16 row-major. vcn: (B,512,4096) bf16. ot: (B,4096,512) bf16.
__global__ __launch_bounds__(512, 2) void flash_attn(
    const unsigned short* __restrict__ qt, const unsigned short* __restrict__ kt,
    const unsigned short* __restrict__ vcn, unsigned short* __restrict__ ot) {
  __shared__ __align__(16) unsigned short K_lds[2][KVB * CDIM];  // 2x64KB, swizzled chunks
  __shared__ __align__(16) unsigned short P_lds[QB][KVB + 8];    // +8 pad breaks conflicts
  __shared__ float redm[QB][2];
  __shared__ float redl[QB][2];

  const int tid = threadIdx.x;
  const int w = tid >> 6, lane = tid & 63;
  const int rs = w >> 1, h = w & 1;
  const int fr = lane & 15, qg = lane >> 4;
  const int bb = blockIdx.y;
  const int q0 = blockIdx.x * QB;
  const float sc = 0.044194173824159216f;  // 512^-0.5

  const unsigned short* Kb = kt  + (size_t)bb * NSP * CDIM;
  const unsigned short* Vb = vcn + (size_t)bb * CDIM * NSP;

  // Q strip: rows q0+16rs+fr, all 512 k -> 16 bf16x8 frags (64 VGPR)
  bf16x8 q[16];
  {
    const unsigned short* Qr = qt + ((size_t)bb * NSP + q0 + 16 * rs + fr) * CDIM;
#pragma unroll
    for (int ks = 0; ks < 16; ++ks) q[ks] = *(const bf16x8*)&Qr[ks * 32 + qg * 8];
  }

  // stage K tile jt (64 rows x 512) into K_lds[buf], XOR-swizzled 16B chunks:
  // LDS chunk c of local row lr holds global chunk c^(lr&7).
  auto stage = [&](int jt, int buf) {
#pragma unroll
    for (int i = 0; i < 8; ++i) {
      const int lr = w * 8 + i;  // lr&7 == i
      async_copy16(Kb + (size_t)(jt * KVB + lr) * CDIM + ((lane ^ i) << 3),
                   &K_lds[buf][lr * CDIM + lane * 8]);
    }
  };

  f32x4 o[4][4] = {};          // O[64 rows][64 cols of this wave]
  float m_full[16], l_full[16];
#pragma unroll
  for (int i = 0; i < 16; ++i) { m_full[i] = -1e30f; l_full[i] = 0.f; }

  stage(0, 0);
  __syncthreads();

  int cur = 0;
  const int NT = NSP / KVB;  // 64
  for (int t = 0; t < NT; ++t) {
    if (t + 1 < NT) stage(t + 1, cur ^ 1);

    // V frags for this tile (direct from L2; vcn[c][j] is B-frag layout)
    const int j0 = t * KVB;
    bf16x8 vfr[4][2];
#pragma unroll
    for (int nf = 0; nf < 4; ++nf)
#pragma unroll
      for (int ks = 0; ks < 2; ++ks)
        vfr[nf][ks] = *(const bf16x8*)&Vb[(size_t)(64 * w + nf * 16 + fr) * NSP +
                                          j0 + ks * 32 + qg * 8];

    // QK^T: S strip 16 rows x 32 cols (2 n-frags), K from swizzled LDS
    f32x4 s0 = {}, s1 = {};
    const unsigned short* Kc = &K_lds[cur][0];
    const int sx = fr & 7;  // row&7 for both n-frags (rows 32h+fr, 32h+16+fr)
#pragma unroll
    for (int ks = 0; ks < 16; ++ks) {
      const int ch = (ks * 4 + qg) ^ sx;
      bf16x8 k0 = *(const bf16x8*)&Kc[(32 * h + fr) * CDIM + ch * 8];
      bf16x8 k1 = *(const bf16x8*)&Kc[(32 * h + 16 + fr) * CDIM + ch * 8];
      s0 = __builtin_amdgcn_mfma_f32_16x16x32_bf16(q[ks], k0, s0, 0, 0, 0);
      s1 = __builtin_amdgcn_mfma_f32_16x16x32_bf16(q[ks], k1, s1, 0, 0, 0);
    }

    // scale + partial row-max over this wave's 32 cols
    float pm[4];
#pragma unroll
    for (int r = 0; r < 4; ++r) {
      s0[r] *= sc; s1[r] *= sc;
      pm[r] = fmaxf(s0[r], s1[r]);
    }
#pragma unroll
    for (int off = 1; off < 16; off <<= 1)
#pragma unroll
      for (int r = 0; r < 4; ++r) pm[r] = fmaxf(pm[r], __shfl_xor(pm[r], off));
    if (fr == 0) {
#pragma unroll
      for (int r = 0; r < 4; ++r) redm[16 * rs + qg * 4 + r][h] = pm[r];
    }
    __syncthreads();  // b1 (also drains K prefetch + V loads)

    // combined max, defer-max rescale decision (identical across all waves)
    float cm[16];
#pragma unroll
    for (int mf = 0; mf < 4; ++mf) {
      float4 a = *(const float4*)&redm[mf * 16 + qg * 4][0];
      float4 b2 = *(const float4*)&redm[mf * 16 + qg * 4 + 2][0];
      cm[mf * 4 + 0] = fmaxf(a.x, a.y);  cm[mf * 4 + 1] = fmaxf(a.z, a.w);
      cm[mf * 4 + 2] = fmaxf(b2.x, b2.y); cm[mf * 4 + 3] = fmaxf(b2.z, b2.w);
    }
    float grow = -1e30f;
#pragma unroll
    for (int i = 0; i < 16; ++i) grow = fmaxf(grow, cm[i] - m_full[i]);
    if (!__all(grow <= 9.0f)) {
      float fs[16];
#pragma unroll
      for (int i = 0; i < 16; ++i) {
        float nm = fmaxf(m_full[i], cm[i]);
        fs[i] = __expf(m_full[i] - nm);
        m_full[i] = nm;
        l_full[i] *= fs[i];
      }
#pragma unroll
      for (int mf = 0; mf < 4; ++mf)
#pragma unroll
        for (int nf = 0; nf < 4; ++nf)
#pragma unroll
          for (int r = 0; r < 4; ++r) o[mf][nf][r] *= fs[mf * 4 + r];
    }

    // P = exp(S - m) for this wave's strip; partial row-sums; P -> LDS bf16
    float psum[4];
#pragma unroll
    for (int r = 0; r < 4; ++r) {
      const int mi = rs * 4 + r;
      float p0 = __expf(s0[r] - m_full[mi]);
      float p1 = __expf(s1[r] - m_full[mi]);
      psum[r] = p0 + p1;
      P_lds[16 * rs + qg * 4 + r][32 * h + fr]      = f2bf(p0);
      P_lds[16 * rs + qg * 4 + r][32 * h + 16 + fr] = f2bf(p1);
    }
#pragma unroll
    for (int off = 1; off < 16; off <<= 1)
#pragma unroll
      for (int r = 0; r < 4; ++r) psum[r] += __shfl_xor(psum[r], off);
    if (fr == 0) {
#pragma unroll
      for (int r = 0; r < 4; ++r) redl[16 * rs + qg * 4 + r][h] = psum[r];
    }
    __syncthreads();  // b2

    // l update (all waves track all 64 rows)
#pragma unroll
    for (int mf = 0; mf < 4; ++mf) {
      float4 a = *(const float4*)&redl[mf * 16 + qg * 4][0];
      float4 b2 = *(const float4*)&redl[mf * 16 + qg * 4 + 2][0];
      l_full[mf * 4 + 0] += a.x + a.y;  l_full[mf * 4 + 1] += a.z + a.w;
      l_full[mf * 4 + 2] += b2.x + b2.y; l_full[mf * 4 + 3] += b2.z + b2.w;
    }

    // PV: O += P(64xKVB) @ V^T   (A from P_lds, B = vfr)
#pragma unroll
    for (int ks = 0; ks < 2; ++ks) {
      bf16x8 pa[4];
#pragma unroll
      for (int mf = 0; mf < 4; ++mf)
        pa[mf] = *(const bf16x8*)&P_lds[mf * 16 + fr][ks * 32 + qg * 8];
#pragma unroll
      for (int mf = 0; mf < 4; ++mf)
#pragma unroll
        for (int nf = 0; nf < 4; ++nf)
          o[mf][nf] = __builtin_amdgcn_mfma_f32_16x16x32_bf16(pa[mf], vfr[nf][ks],
                                                              o[mf][nf], 0, 0, 0);
    }
    __syncthreads();  // b3: P_lds consumed; safe to overwrite next tile
    cur ^= 1;
  }

  // epilogue: O /= l, write ot[b][row][col] bf16
  unsigned short* Ob = ot + (size_t)bb * NSP * CDIM;
  float inv[16];
#pragma unroll
  for (int i = 0; i < 16; ++i) inv[i] = 1.f / l_full[i];
#pragma unroll
  for (int mf = 0; mf < 4; ++mf)
#pragma unroll
    for (int nf = 0; nf < 4; ++nf)
#pragma unroll
      for (int r = 0; r < 4; ++r) {
        int gr = q0 + mf * 16 + qg * 4 + r;
        int gc = 64 * w + nf * 16 + fr;
        Ob[(size_t)gr * CDIM + gc] = f2bf(o[mf][nf][r] * inv[mf * 4 + r]);
      }
}

extern "C" void kernel_launch(void* const* d_in, const int* in_sizes, int n_in,
                              void* d_out, int out_size, void* d_ws, size_t ws_size,
                              hipStream_t stream) {
  const float* hs  = (const float*)d_in[0];
  const float* gns = (const float*)d_in[1];
  const float* gnb = (const float*)d_in[2];
  const float* wq  = (const float*)d_in[3];
  const float* bq  = (const float*)d_in[4];
  const float* wk  = (const float*)d_in[5];
  const float* bk  = (const float*)d_in[6];
  const float* wv  = (const float*)d_in[7];
  const float* bv  = (const float*)d_in[8];
  const float* wp  = (const float*)d_in[9];
  const float* bp  = (const float*)d_in[10];

  char* p = (char*)d_ws;
  unsigned short* wqb = (unsigned short*)p; p += (size_t)CDIM * CDIM * 2;
  unsigned short* wkb = (unsigned short*)p; p += (size_t)CDIM * CDIM * 2;
  unsigned short* wvb = (unsigned short*)p; p += (size_t)CDIM * CDIM * 2;
  unsigned short* wpb = (unsigned short*)p; p += (size_t)CDIM * CDIM * 2;
  const size_t bn = (size_t)NSP * CDIM;  // 2M elements per batch
  unsigned short* hnt = (unsigned short*)p; p += NB * bn * 2;
  unsigned short* qt  = (unsigned short*)p; p += NB * bn * 2;
  unsigned short* kt  = (unsigned short*)p; p += NB * bn * 2;
  unsigned short* vcn = (unsigned short*)p; p += NB * bn * 2;
  unsigned short* ot  = (unsigned short*)p; p += NB * bn * 2;
  float* stats = (float*)p;      p += 256 * 4;

  weights_to_bf16<<<dim3(256, 4), 256, 0, stream>>>(wq, wk, wv, wp, wqb, wkb, wvb, wpb);
  gn_stats<<<128, 256, 0, stream>>>(hs, stats);
  norm_transpose<<<dim3(64, 8, 4), 256, 0, stream>>>(hs, stats, gns, gnb, hnt);

  const long sBN = (long)bn;
  // Qt[b] (4096x512) = Hnt[b] @ Wq^T + bq (per-col)
  gemm_nt<2, 1, 0><<<dim3(4, 32, NB), 256, 0, stream>>>(
      hnt, wqb, qt, bq, nullptr, NSP, CDIM, CDIM, 1.f, sBN, 0, sBN, 0);
  gemm_nt<2, 1, 0><<<dim3(4, 32, NB), 256, 0, stream>>>(
      hnt, wkb, kt, bk, nullptr, NSP, CDIM, CDIM, 1.f, sBN, 0, sBN, 0);
  // Vcn[b] (512x4096) = Wv @ Hnt[b]^T + bv (per-row)
  gemm_nt<1, 1, 0><<<dim3(32, 4, NB), 256, 0, stream>>>(
      wvb, hnt, vcn, bv, nullptr, CDIM, NSP, CDIM, 1.f, 0, sBN, sBN, 0);

  // fused attention: Ot[b] (4096x512) = softmax(Qt Kt^T * C^-0.5) @ Vcn^T
  flash_attn<<<dim3(64, NB), 512, 0, stream>>>(qt, kt, vcn, ot);

  // out[b] (512x4096 fp32) = Wp @ Ot[b]^T + bp (per-row) + residual
  gemm_nt<1, 0, 1><<<dim3(32, 4, NB), 256, 0, stream>>>(
      wpb, ot, (float*)d_out, bp, hs, CDIM, NSP, CDIM, 1.f, 0, sBN, sBN, sBN);
}

// Round 4
// 397.798 us; speedup vs baseline: 1.9930x; 1.9930x over previous
//
#include <hip/hip_runtime.h>
#include <cstdint>
#include <cstddef>

// AttnBlock: B=4, C=512, H=W=64 (N=4096). All-fp32 I/O, bf16 MFMA internally.
// R4: staged pipeline (R2 base), but softmax eliminated:
//   qk_exp writes P = exp(s*sc - M0) bf16 directly (fixed offset, no row max)
//   + row-sum l via atomics; PV = plain split-K GEMM on P; ot = sum(Op)/l.

#define CDIM 512
#define NSP  4096
#define NB   4
#define M0   12.0f

using bf16x8 = __attribute__((ext_vector_type(8))) __bf16;
using f32x4  = __attribute__((ext_vector_type(4))) float;
using u16x4  = __attribute__((ext_vector_type(4))) unsigned short;
using h8     = __attribute__((ext_vector_type(8))) _Float16;

__device__ __forceinline__ unsigned short f2bf(float f) {
  unsigned int u = __float_as_uint(f);
  u += 0x7fffu + ((u >> 16) & 1u);
  return (unsigned short)(u >> 16);
}

__device__ __forceinline__ void async_copy16(const unsigned short* g, unsigned short* l) {
  __builtin_amdgcn_global_load_lds(
      (const __attribute__((address_space(1))) void*)g,
      (__attribute__((address_space(3))) void*)l, 16, 0, 0);
}

// ---------------- GroupNorm stats: one block per (b, group) ----------------
__global__ __launch_bounds__(256) void gn_stats(const float* __restrict__ x,
                                                float* __restrict__ stats) {
  const size_t base = (size_t)blockIdx.x * 65536;  // 16 ch * 4096, contiguous
  const float4* p = (const float4*)(x + base);
  float s = 0.f, ss = 0.f;
  for (int i = threadIdx.x; i < 16384; i += 256) {
    float4 v = p[i];
    s  += v.x + v.y + v.z + v.w;
    ss += v.x*v.x + v.y*v.y + v.z*v.z + v.w*v.w;
  }
  for (int off = 32; off; off >>= 1) {
    s  += __shfl_xor(s, off);
    ss += __shfl_xor(ss, off);
  }
  __shared__ float rs[4], rss[4];
  const int w = threadIdx.x >> 6;
  if ((threadIdx.x & 63) == 0) { rs[w] = s; rss[w] = ss; }
  __syncthreads();
  if (threadIdx.x == 0) {
    float S  = rs[0] + rs[1] + rs[2] + rs[3];
    float SS = rss[0] + rss[1] + rss[2] + rss[3];
    float mean = S * (1.f / 65536.f);
    float var  = SS * (1.f / 65536.f) - mean * mean;
    stats[2 * blockIdx.x]     = mean;
    stats[2 * blockIdx.x + 1] = rsqrtf(var + 1e-6f);
  }
}

// ------------- normalize + transpose: x(B,C,N) f32 -> Hnt(B,N,C) bf16 -------
__global__ __launch_bounds__(256) void norm_transpose(
    const float* __restrict__ x, const float* __restrict__ stats,
    const float* __restrict__ gns, const float* __restrict__ gnb,
    unsigned short* __restrict__ hnt) {
  __shared__ float tile[64][65];
  const int b  = blockIdx.z;
  const int c0 = blockIdx.y * 64, n0 = blockIdx.x * 64;
  const int tx = threadIdx.x & 63, ty = threadIdx.x >> 6;
  for (int i = 0; i < 16; ++i) {
    int cl = ty * 16 + i;
    int c  = c0 + cl;
    int g  = c >> 4;
    float mean = stats[(b * 32 + g) * 2];
    float rstd = stats[(b * 32 + g) * 2 + 1];
    float v = x[((size_t)(b * CDIM + c)) * NSP + n0 + tx];
    tile[cl][tx] = (v - mean) * rstd * gns[c] + gnb[c];
  }
  __syncthreads();
  for (int i = 0; i < 16; ++i) {
    int nl = ty * 16 + i;
    hnt[((size_t)(b * NSP + n0 + nl)) * CDIM + c0 + tx] = f2bf(tile[tx][nl]);
  }
}

// ---------------- fp32 -> bf16 weight conversion (4 weights, one launch) ----
__global__ __launch_bounds__(256) void weights_to_bf16(
    const float* __restrict__ w0, const float* __restrict__ w1,
    const float* __restrict__ w2, const float* __restrict__ w3,
    unsigned short* __restrict__ o0, unsigned short* __restrict__ o1,
    unsigned short* __restrict__ o2, unsigned short* __restrict__ o3) {
  const float* s; unsigned short* o;
  switch (blockIdx.y) {
    case 0: s = w0; o = o0; break;
    case 1: s = w1; o = o1; break;
    case 2: s = w2; o = o2; break;
    default: s = w3; o = o3; break;
  }
  int i = blockIdx.x * 256 + threadIdx.x;
  float4 v = ((const float4*)s)[i];
  u16x4 r = {f2bf(v.x), f2bf(v.y), f2bf(v.z), f2bf(v.w)};
  *(u16x4*)(o + (size_t)i * 4) = r;
}

// ---------------- NT GEMM: D[M,N] = A[M,K] @ Bt[N,K]^T ----------------
// BIAS_MODE: 0 none, 1 per-row bias[m], 2 per-col bias[n]
// OUT_MODE:  0 f32, 1 bf16, 2 fp16
// SPLITK:    blockIdx.z = split*NB + b; k-range [split*kLen,+kLen); D off z*M*N
// EXPL:      store exp(fma(acc,scale,-M0)); accumulate row sums into lsum[b*M+row]
template <int BIAS_MODE, int OUT_MODE, int RESID, int SPLITK, int EXPL>
__global__ __launch_bounds__(256) void gemm_nt(
    const unsigned short* __restrict__ A, const unsigned short* __restrict__ Bt,
    void* __restrict__ Dv, const float* __restrict__ bias,
    const float* __restrict__ resid, float* __restrict__ lsum,
    int M, int N, int K, float scale,
    long sA, long sB, long sD, long sR, int kLen) {
  __shared__ unsigned short lsA[2][128 * 32];
  __shared__ unsigned short lsB[2][128 * 32];
  const int tid = threadIdx.x;
  const int w = tid >> 6, lane = tid & 63;
  const int wr = w >> 1, wc = w & 1;
  const int b = SPLITK ? (blockIdx.z & 3) : blockIdx.z;
  const int bm0 = blockIdx.y * 128, bn0 = blockIdx.x * 128;
  const unsigned short* Ab = A + (size_t)b * sA;
  const unsigned short* Bb = Bt + (size_t)b * sB;
  const size_t dOff = SPLITK ? (size_t)blockIdx.z * (size_t)M * N
                             : (size_t)b * (size_t)sD;
  const int kStart = SPLITK ? (blockIdx.z >> 2) * kLen : 0;
  const int kEnd   = SPLITK ? kStart + kLen : K;

  f32x4 acc[4][4] = {};
  const int r0  = w * 16 + (lane >> 2);
  const int kof = (lane & 3) * 8;
  const int fr  = lane & 15, kf = (lane >> 4) * 8;

  for (int it = 0; it < 2; ++it) {
    int row = it * 64 + r0;
    async_copy16(Ab + (size_t)(bm0 + row) * K + kStart + kof, &lsA[0][row * 32 + kof]);
    async_copy16(Bb + (size_t)(bn0 + row) * K + kStart + kof, &lsB[0][row * 32 + kof]);
  }
  __syncthreads();

  int cur = 0;
  for (int k0 = kStart; k0 < kEnd; k0 += 32) {
    const int nk = k0 + 32;
    if (nk < kEnd) {
      for (int it = 0; it < 2; ++it) {
        int row = it * 64 + r0;
        async_copy16(Ab + (size_t)(bm0 + row) * K + nk + kof, &lsA[cur ^ 1][row * 32 + kof]);
        async_copy16(Bb + (size_t)(bn0 + row) * K + nk + kof, &lsB[cur ^ 1][row * 32 + kof]);
      }
    }
    bf16x8 af[4], bff[4];
    for (int i = 0; i < 4; ++i) {
      af[i]  = *(const bf16x8*)(&lsA[cur][(wr * 64 + i * 16 + fr) * 32 + kf]);
      bff[i] = *(const bf16x8*)(&lsB[cur][(wc * 64 + i * 16 + fr) * 32 + kf]);
    }
    for (int i = 0; i < 4; ++i)
      for (int j = 0; j < 4; ++j)
        acc[i][j] = __builtin_amdgcn_mfma_f32_16x16x32_bf16(af[i], bff[j], acc[i][j], 0, 0, 0);
    __syncthreads();
    cur ^= 1;
  }

  const int col_l = lane & 15, row_l = (lane >> 4) * 4;
  float rs[4][4];
  if (EXPL)
    for (int i = 0; i < 4; ++i)
      for (int r = 0; r < 4; ++r) rs[i][r] = 0.f;

  for (int i = 0; i < 4; ++i)
    for (int j = 0; j < 4; ++j) {
      int gr = bm0 + wr * 64 + i * 16 + row_l;
      int gc = bn0 + wc * 64 + j * 16 + col_l;
      for (int r = 0; r < 4; ++r) {
        float v;
        if (EXPL) {
          v = __expf(fmaf(acc[i][j][r], scale, -M0));
          rs[i][r] += v;
        } else {
          v = acc[i][j][r] * scale;
          if (BIAS_MODE == 1) v += bias[gr + r];
          if (BIAS_MODE == 2) v += bias[gc];
          if (RESID) v += resid[(size_t)b * sR + (size_t)(gr + r) * N + gc];
        }
        if (OUT_MODE == 1)
          ((unsigned short*)Dv)[dOff + (size_t)(gr + r) * N + gc] = f2bf(v);
        else if (OUT_MODE == 2)
          ((_Float16*)Dv)[dOff + (size_t)(gr + r) * N + gc] = (_Float16)v;
        else
          ((float*)Dv)[dOff + (size_t)(gr + r) * N + gc] = v;
      }
    }

  if (EXPL) {
    // reduce each (i,r) row partial across the 16 col lanes, then atomicAdd
#pragma unroll
    for (int i = 0; i < 4; ++i)
#pragma unroll
      for (int r = 0; r < 4; ++r) {
        float v = rs[i][r];
        v += __shfl_xor(v, 1); v += __shfl_xor(v, 2);
        v += __shfl_xor(v, 4); v += __shfl_xor(v, 8);
        if (col_l == 0) {
          int gr = bm0 + wr * 64 + i * 16 + row_l + r;
          atomicAdd(&lsum[(size_t)b * M + gr], v);
        }
      }
  }
}

// ---------------- reduce: ot = (Op0 + Op1) / l  -> bf16 ----------------
__global__ __launch_bounds__(256) void reduce_div(const _Float16* __restrict__ Op,
                                                  const float* __restrict__ l,
                                                  unsigned short* __restrict__ ot) {
  const size_t stride = (size_t)NB * NSP * CDIM;  // elems per split
  size_t base = ((size_t)blockIdx.x * 256 + threadIdx.x) * 8;
  float linv = 1.f / l[base >> 9];  // row = base / 512
  h8 a = *(const h8*)(Op + base);
  h8 c = *(const h8*)(Op + stride + base);
  u16x4 o0, o1;
#pragma unroll
  for (int i = 0; i < 4; ++i) {
    o0[i] = f2bf(((float)a[i] + (float)c[i]) * linv);
    o1[i] = f2bf(((float)a[i + 4] + (float)c[i + 4]) * linv);
  }
  *(u16x4*)(ot + base) = o0;
  *(u16x4*)(ot + base + 4) = o1;
}

extern "C" void kernel_launch(void* const* d_in, const int* in_sizes, int n_in,
                              void* d_out, int out_size, void* d_ws, size_t ws_size,
                              hipStream_t stream) {
  const float* hs  = (const float*)d_in[0];
  const float* gns = (const float*)d_in[1];
  const float* gnb = (const float*)d_in[2];
  const float* wq  = (const float*)d_in[3];
  const float* bq  = (const float*)d_in[4];
  const float* wk  = (const float*)d_in[5];
  const float* bk  = (const float*)d_in[6];
  const float* wv  = (const float*)d_in[7];
  const float* bv  = (const float*)d_in[8];
  const float* wp  = (const float*)d_in[9];
  const float* bp  = (const float*)d_in[10];

  char* p = (char*)d_ws;
  unsigned short* wqb = (unsigned short*)p; p += (size_t)CDIM * CDIM * 2;
  unsigned short* wkb = (unsigned short*)p; p += (size_t)CDIM * CDIM * 2;
  unsigned short* wvb = (unsigned short*)p; p += (size_t)CDIM * CDIM * 2;
  unsigned short* wpb = (unsigned short*)p; p += (size_t)CDIM * CDIM * 2;
  const size_t bn = (size_t)NSP * CDIM;  // 2M elements per batch
  unsigned short* hnt = (unsigned short*)p; p += NB * bn * 2;   // also reused as ot
  unsigned short* qt  = (unsigned short*)p; p += NB * bn * 2;
  unsigned short* kt  = (unsigned short*)p; p += NB * bn * 2;
  unsigned short* vcn = (unsigned short*)p; p += NB * bn * 2;
  unsigned short* P   = (unsigned short*)p; p += (size_t)NB * NSP * NSP * 2;  // 128 MiB
  _Float16* Op = (_Float16*)p;  p += (size_t)2 * NB * bn * 2;   // 32 MiB (2 splits)
  float* lsum  = (float*)p;     p += (size_t)NB * NSP * 4;      // 64 KiB
  float* stats = (float*)p;     p += 256 * 4;
  unsigned short* ot = hnt;  // hnt dead after the QKV projections

  hipMemsetAsync(lsum, 0, (size_t)NB * NSP * 4, stream);
  weights_to_bf16<<<dim3(256, 4), 256, 0, stream>>>(wq, wk, wv, wp, wqb, wkb, wvb, wpb);
  gn_stats<<<128, 256, 0, stream>>>(hs, stats);
  norm_transpose<<<dim3(64, 8, 4), 256, 0, stream>>>(hs, stats, gns, gnb, hnt);

  const long sBN = (long)bn;
  const long sPP = (long)NSP * NSP;
  // Qt[b] (4096x512) = Hnt[b] @ Wq^T + bq (per-col)
  gemm_nt<2, 1, 0, 0, 0><<<dim3(4, 32, NB), 256, 0, stream>>>(
      hnt, wqb, qt, bq, nullptr, nullptr, NSP, CDIM, CDIM, 1.f, sBN, 0, sBN, 0, 0);
  gemm_nt<2, 1, 0, 0, 0><<<dim3(4, 32, NB), 256, 0, stream>>>(
      hnt, wkb, kt, bk, nullptr, nullptr, NSP, CDIM, CDIM, 1.f, sBN, 0, sBN, 0, 0);
  // Vcn[b] (512x4096) = Wv @ Hnt[b]^T + bv (per-row)
  gemm_nt<1, 1, 0, 0, 0><<<dim3(32, 4, NB), 256, 0, stream>>>(
      wvb, hnt, vcn, bv, nullptr, nullptr, CDIM, NSP, CDIM, 1.f, 0, sBN, sBN, 0, 0);

  // P[b] (4096x4096 bf16) = exp(Qt Kt^T * C^-0.5 - M0); lsum[b][i] += row sums
  const float sc = 0.044194173824159216f;  // 512^-0.5
  gemm_nt<0, 1, 0, 0, 1><<<dim3(32, 32, NB), 256, 0, stream>>>(
      qt, kt, P, nullptr, nullptr, lsum, NSP, NSP, CDIM, sc, sBN, sBN, sPP, 0, 0);

  // PV split-K=2: Op[z] (4096x512 fp16) = P[b][:, ks:ks+2048] @ Vcn[b][:, same]^T
  gemm_nt<0, 2, 0, 1, 0><<<dim3(4, 32, 2 * NB), 256, 0, stream>>>(
      P, vcn, Op, nullptr, nullptr, nullptr, NSP, CDIM, NSP, 1.f,
      sPP, sBN, 0, 0, NSP / 2);

  // ot (bf16) = (Op0 + Op1) / lsum
  reduce_div<<<4096, 256, 0, stream>>>(Op, lsum, ot);

  // out[b] (512x4096 fp32) = Wp @ Ot[b]^T + bp (per-row) + residual
  gemm_nt<1, 0, 1, 0, 0><<<dim3(32, 4, NB), 256, 0, stream>>>(
      wpb, ot, (float*)d_out, bp, hs, nullptr, CDIM, NSP, CDIM, 1.f, 0, sBN, sBN, sBN, 0);
}